// Round 2
// baseline (756.928 us; speedup 1.0000x reference)
//
#include <hip/hip_runtime.h>

#define D_FEAT 64
#define SCAN_CHUNK 2048   // 256 threads x 8 elements

// ---------------- zero degree counters ----------------
__global__ void zero_int_kernel(int* __restrict__ p, int n) {
    int i = blockIdx.x * blockDim.x + threadIdx.x;
    if (i < n) p[i] = 0;
}

// ---------------- degree histogram ----------------
__global__ void hist_kernel(const int* __restrict__ ref_a,
                            const int* __restrict__ ref_b,
                            int* __restrict__ deg, int n_edges) {
    int e = blockIdx.x * blockDim.x + threadIdx.x;
    if (e >= n_edges) return;
    atomicAdd(&deg[ref_a[e]], 1);
    atomicAdd(&deg[ref_b[e]], 1);
}

// ---------------- per-chunk exclusive scan ----------------
// Each block scans SCAN_CHUNK elements of deg into row_excl (chunk-local
// exclusive prefix) and writes the chunk total to block_sums[chunk].
__global__ __launch_bounds__(256) void scan_blocks_kernel(
    const int* __restrict__ deg, int* __restrict__ row_excl,
    int* __restrict__ block_sums, int n) {
    int chunk = blockIdx.x;
    int base = chunk * SCAN_CHUNK;
    int tid = threadIdx.x;
    int lane = tid & 63;
    int wid = tid >> 6;

    int vals[8];
    int s = 0;
    #pragma unroll
    for (int i = 0; i < 8; ++i) {
        int idx = base + tid * 8 + i;
        int v = (idx < n) ? deg[idx] : 0;
        vals[i] = s;          // thread-local exclusive prefix
        s += v;
    }
    // wave-inclusive scan of per-thread sums
    int inc = s;
    #pragma unroll
    for (int d = 1; d < 64; d <<= 1) {
        int t = __shfl_up(inc, d);
        if (lane >= d) inc += t;
    }
    __shared__ int wsum[4];
    if (lane == 63) wsum[wid] = inc;
    __syncthreads();
    int wave_off = 0;
    for (int i = 0; i < wid; ++i) wave_off += wsum[i];
    int excl = wave_off + inc - s;    // block-local exclusive prefix of this thread
    #pragma unroll
    for (int i = 0; i < 8; ++i) {
        int idx = base + tid * 8 + i;
        if (idx < n) row_excl[idx] = excl + vals[i];
    }
    if (tid == 255) block_sums[chunk] = wave_off + inc;  // chunk total
}

// ---------------- exclusive scan of chunk totals (single wave, carry loop) ----------------
__global__ void scan_totals_kernel(int* __restrict__ bs, int nchunks) {
    int lane = threadIdx.x;  // blockDim = 64
    int carry = 0;
    for (int base = 0; base < nchunks; base += 64) {
        int i = base + lane;
        int v = (i < nchunks) ? bs[i] : 0;
        int inc = v;
        #pragma unroll
        for (int d = 1; d < 64; d <<= 1) {
            int t = __shfl_up(inc, d);
            if (lane >= d) inc += t;
        }
        if (i < nchunks) bs[i] = carry + inc - v;
        carry += __shfl(inc, 63);
    }
}

// ---------------- add chunk offsets -> row_start; init cursor ----------------
__global__ void add_offsets_kernel(int* __restrict__ row_excl,
                                   const int* __restrict__ bs,
                                   int* __restrict__ cursor, int n, int total) {
    int i = blockIdx.x * blockDim.x + threadIdx.x;
    if (i < n) {
        int r = row_excl[i] + bs[i / SCAN_CHUNK];
        row_excl[i] = r;
        cursor[i] = r;
    }
    if (i == n) row_excl[n] = total;
}

// ---------------- fill adjacency ----------------
__global__ void fill_adj_kernel(const int* __restrict__ ref_a,
                                const int* __restrict__ ref_b,
                                int* __restrict__ cursor,
                                int* __restrict__ adj, int n_edges) {
    int e = blockIdx.x * blockDim.x + threadIdx.x;
    if (e >= n_edges) return;
    int a = ref_a[e];
    int b = ref_b[e];
    int pa = atomicAdd(&cursor[a], 1);
    adj[pa] = b;
    int pb = atomicAdd(&cursor[b], 1);
    adj[pb] = a;
}

// ---------------- fused gather + 2-layer MLP ----------------
// Block = 256 = 4 waves. Each wave owns 4 consecutive nodes (block covers 16).
// Gather: lane j accumulates feature j over neighbors (plain coalesced row
// loads; X is L3-resident). MLP: W staged in LDS; each W-column read feeds 4
// FMAs (4 nodes/wave) to amortize LDS traffic. All hot-loop LDS deps are
// wave-local -> no __syncthreads after the initial weight stage.
__global__ __launch_bounds__(256) void gather_mlp_kernel(
    const float* __restrict__ X,
    const int* __restrict__ row_start,
    const int* __restrict__ adj,
    const float* __restrict__ Wh, const float* __restrict__ bh,
    const float* __restrict__ Wo, const float* __restrict__ bo,
    float* __restrict__ out, int n_nodes) {
    __shared__ __align__(16) float wh_lds[D_FEAT * D_FEAT];
    __shared__ __align__(16) float wo_lds[D_FEAT * D_FEAT];
    __shared__ __align__(16) float x_lds[4][4][D_FEAT];
    __shared__ __align__(16) float h_lds[4][4][D_FEAT];

    int tid = threadIdx.x;
    {
        const float4* Wh4 = (const float4*)Wh;
        const float4* Wo4 = (const float4*)Wo;
        float4* wh4 = (float4*)wh_lds;
        float4* wo4 = (float4*)wo_lds;
        for (int i = tid; i < D_FEAT * D_FEAT / 4; i += 256) {
            wh4[i] = Wh4[i];
            wo4[i] = Wo4[i];
        }
    }
    int w = tid >> 6;
    int j = tid & 63;
    float bhj = bh[j];
    float boj = bo[j];
    __syncthreads();

    int vbase = blockIdx.x * 16 + w * 4;

    // ---- gather 4 nodes (independent chains for ILP) ----
    #pragma unroll
    for (int nb = 0; nb < 4; ++nb) {
        int v = vbase + nb;
        float acc = 0.0f;
        if (v < n_nodes) {
            acc = X[v * D_FEAT + j];
            int k = row_start[v];
            int kend = row_start[v + 1];
            for (; k + 4 <= kend; k += 4) {
                int u0 = adj[k], u1 = adj[k + 1], u2 = adj[k + 2], u3 = adj[k + 3];
                acc += X[u0 * D_FEAT + j];
                acc += X[u1 * D_FEAT + j];
                acc += X[u2 * D_FEAT + j];
                acc += X[u3 * D_FEAT + j];
            }
            for (; k < kend; ++k) acc += X[adj[k] * D_FEAT + j];
        }
        x_lds[w][nb][j] = acc;
    }

    // ---- layer 1: h = relu(x @ Wh + bh), 4 nodes per wave ----
    {
        float a0 = bhj, a1 = bhj, a2 = bhj, a3 = bhj;
        const float4* x0 = (const float4*)x_lds[w][0];
        const float4* x1 = (const float4*)x_lds[w][1];
        const float4* x2 = (const float4*)x_lds[w][2];
        const float4* x3 = (const float4*)x_lds[w][3];
        #pragma unroll
        for (int k4 = 0; k4 < 16; ++k4) {
            float4 p0 = x0[k4], p1 = x1[k4], p2 = x2[k4], p3 = x3[k4];
            float w0 = wh_lds[(k4 * 4 + 0) * D_FEAT + j];
            float w1 = wh_lds[(k4 * 4 + 1) * D_FEAT + j];
            float w2 = wh_lds[(k4 * 4 + 2) * D_FEAT + j];
            float w3 = wh_lds[(k4 * 4 + 3) * D_FEAT + j];
            a0 = fmaf(p0.x, w0, a0); a0 = fmaf(p0.y, w1, a0); a0 = fmaf(p0.z, w2, a0); a0 = fmaf(p0.w, w3, a0);
            a1 = fmaf(p1.x, w0, a1); a1 = fmaf(p1.y, w1, a1); a1 = fmaf(p1.z, w2, a1); a1 = fmaf(p1.w, w3, a1);
            a2 = fmaf(p2.x, w0, a2); a2 = fmaf(p2.y, w1, a2); a2 = fmaf(p2.z, w2, a2); a2 = fmaf(p2.w, w3, a2);
            a3 = fmaf(p3.x, w0, a3); a3 = fmaf(p3.y, w1, a3); a3 = fmaf(p3.z, w2, a3); a3 = fmaf(p3.w, w3, a3);
        }
        h_lds[w][0][j] = fmaxf(a0, 0.0f);
        h_lds[w][1][j] = fmaxf(a1, 0.0f);
        h_lds[w][2][j] = fmaxf(a2, 0.0f);
        h_lds[w][3][j] = fmaxf(a3, 0.0f);
    }

    // ---- layer 2: out = relu(h @ Wo + bo) ----
    {
        float a0 = boj, a1 = boj, a2 = boj, a3 = boj;
        const float4* x0 = (const float4*)h_lds[w][0];
        const float4* x1 = (const float4*)h_lds[w][1];
        const float4* x2 = (const float4*)h_lds[w][2];
        const float4* x3 = (const float4*)h_lds[w][3];
        #pragma unroll
        for (int k4 = 0; k4 < 16; ++k4) {
            float4 p0 = x0[k4], p1 = x1[k4], p2 = x2[k4], p3 = x3[k4];
            float w0 = wo_lds[(k4 * 4 + 0) * D_FEAT + j];
            float w1 = wo_lds[(k4 * 4 + 1) * D_FEAT + j];
            float w2 = wo_lds[(k4 * 4 + 2) * D_FEAT + j];
            float w3 = wo_lds[(k4 * 4 + 3) * D_FEAT + j];
            a0 = fmaf(p0.x, w0, a0); a0 = fmaf(p0.y, w1, a0); a0 = fmaf(p0.z, w2, a0); a0 = fmaf(p0.w, w3, a0);
            a1 = fmaf(p1.x, w0, a1); a1 = fmaf(p1.y, w1, a1); a1 = fmaf(p1.z, w2, a1); a1 = fmaf(p1.w, w3, a1);
            a2 = fmaf(p2.x, w0, a2); a2 = fmaf(p2.y, w1, a2); a2 = fmaf(p2.z, w2, a2); a2 = fmaf(p2.w, w3, a2);
            a3 = fmaf(p3.x, w0, a3); a3 = fmaf(p3.y, w1, a3); a3 = fmaf(p3.z, w2, a3); a3 = fmaf(p3.w, w3, a3);
        }
        int v0 = vbase;
        if (v0 + 0 < n_nodes) out[(v0 + 0) * D_FEAT + j] = fmaxf(a0, 0.0f);
        if (v0 + 1 < n_nodes) out[(v0 + 1) * D_FEAT + j] = fmaxf(a1, 0.0f);
        if (v0 + 2 < n_nodes) out[(v0 + 2) * D_FEAT + j] = fmaxf(a2, 0.0f);
        if (v0 + 3 < n_nodes) out[(v0 + 3) * D_FEAT + j] = fmaxf(a3, 0.0f);
    }
}

extern "C" void kernel_launch(void* const* d_in, const int* in_sizes, int n_in,
                              void* d_out, int out_size, void* d_ws, size_t ws_size,
                              hipStream_t stream) {
    const float* X     = (const float*)d_in[0];
    const int*   ref_a = (const int*)d_in[1];
    const int*   ref_b = (const int*)d_in[2];
    // d_in[3]=v_map, d_in[4]=v_count : unused by the reference
    const float* Wh    = (const float*)d_in[5];
    const float* bh    = (const float*)d_in[6];
    const float* Wo    = (const float*)d_in[7];
    const float* bo    = (const float*)d_in[8];
    float* out = (float*)d_out;

    int n_nodes = in_sizes[0] / D_FEAT;
    int n_edges = in_sizes[1];
    int nchunks = (n_nodes + SCAN_CHUNK - 1) / SCAN_CHUNK;

    // workspace layout (all int32): ~9.3 MB total
    int* deg       = (int*)d_ws;
    int* row_start = deg + n_nodes;          // n_nodes + 1
    int* cursor    = row_start + n_nodes + 1;
    int* bs        = cursor + n_nodes;
    int* adj       = bs + ((nchunks + 3) & ~3);  // 2 * n_edges

    int nb256 = (n_nodes + 255) / 256;
    int eb256 = (n_edges + 255) / 256;

    zero_int_kernel<<<nb256, 256, 0, stream>>>(deg, n_nodes);
    hist_kernel<<<eb256, 256, 0, stream>>>(ref_a, ref_b, deg, n_edges);
    scan_blocks_kernel<<<nchunks, 256, 0, stream>>>(deg, row_start, bs, n_nodes);
    scan_totals_kernel<<<1, 64, 0, stream>>>(bs, nchunks);
    add_offsets_kernel<<<(n_nodes + 256) / 256, 256, 0, stream>>>(
        row_start, bs, cursor, n_nodes, 2 * n_edges);
    fill_adj_kernel<<<eb256, 256, 0, stream>>>(ref_a, ref_b, cursor, adj, n_edges);

    int gblocks = (n_nodes + 15) / 16;
    gather_mlp_kernel<<<gblocks, 256, 0, stream>>>(
        X, row_start, adj, Wh, bh, Wo, bo, out, n_nodes);
}

// Round 3
// 532.909 us; speedup vs baseline: 1.4204x; 1.4204x over previous
//
#include <hip/hip_runtime.h>

#define D_FEAT 64
#define SCAN_CHUNK 2048   // 256 threads x 8 elements

// ---------------- degree histogram ----------------
__global__ void hist_kernel(const int* __restrict__ ref_a,
                            const int* __restrict__ ref_b,
                            int* __restrict__ deg, int n_edges) {
    int e = blockIdx.x * blockDim.x + threadIdx.x;
    if (e >= n_edges) return;
    atomicAdd(&deg[ref_a[e]], 1);
    atomicAdd(&deg[ref_b[e]], 1);
}

// ---------------- per-chunk exclusive scan ----------------
__global__ __launch_bounds__(256) void scan_blocks_kernel(
    const int* __restrict__ deg, int* __restrict__ row_excl,
    int* __restrict__ block_sums, int n) {
    int chunk = blockIdx.x;
    int base = chunk * SCAN_CHUNK;
    int tid = threadIdx.x;
    int lane = tid & 63;
    int wid = tid >> 6;

    int vals[8];
    int s = 0;
    #pragma unroll
    for (int i = 0; i < 8; ++i) {
        int idx = base + tid * 8 + i;
        int v = (idx < n) ? deg[idx] : 0;
        vals[i] = s;
        s += v;
    }
    int inc = s;
    #pragma unroll
    for (int d = 1; d < 64; d <<= 1) {
        int t = __shfl_up(inc, d);
        if (lane >= d) inc += t;
    }
    __shared__ int wsum[4];
    if (lane == 63) wsum[wid] = inc;
    __syncthreads();
    int wave_off = 0;
    for (int i = 0; i < wid; ++i) wave_off += wsum[i];
    int excl = wave_off + inc - s;
    #pragma unroll
    for (int i = 0; i < 8; ++i) {
        int idx = base + tid * 8 + i;
        if (idx < n) row_excl[idx] = excl + vals[i];
    }
    if (tid == 255) block_sums[chunk] = wave_off + inc;
}

// ---------------- exclusive scan of chunk totals ----------------
__global__ void scan_totals_kernel(int* __restrict__ bs, int nchunks) {
    int lane = threadIdx.x;  // blockDim = 64
    int carry = 0;
    for (int base = 0; base < nchunks; base += 64) {
        int i = base + lane;
        int v = (i < nchunks) ? bs[i] : 0;
        int inc = v;
        #pragma unroll
        for (int d = 1; d < 64; d <<= 1) {
            int t = __shfl_up(inc, d);
            if (lane >= d) inc += t;
        }
        if (i < nchunks) bs[i] = carry + inc - v;
        carry += __shfl(inc, 63);
    }
}

// ---------------- add chunk offsets -> row_start; init cursor ----------------
__global__ void add_offsets_kernel(int* __restrict__ row_excl,
                                   const int* __restrict__ bs,
                                   int* __restrict__ cursor, int n, int total) {
    int i = blockIdx.x * blockDim.x + threadIdx.x;
    if (i < n) {
        int r = row_excl[i] + bs[i / SCAN_CHUNK];
        row_excl[i] = r;
        cursor[i] = r;
    }
    if (i == n) row_excl[n] = total;
}

// ---------------- fill adjacency ----------------
__global__ void fill_adj_kernel(const int* __restrict__ ref_a,
                                const int* __restrict__ ref_b,
                                int* __restrict__ cursor,
                                int* __restrict__ adj, int n_edges) {
    int e = blockIdx.x * blockDim.x + threadIdx.x;
    if (e >= n_edges) return;
    int a = ref_a[e];
    int b = ref_b[e];
    int pa = atomicAdd(&cursor[a], 1);
    adj[pa] = b;
    int pb = atomicAdd(&cursor[b], 1);
    adj[pb] = a;
}

// ---------------- gather only: agg[v] = X[v] + sum_{u in N(v)} X[u] ----------------
// One wave per node, lane = feature. Slim kernel: no LDS, low VGPR -> max
// occupancy so the random-row L2-miss stream has enough outstanding loads.
// 8 independent row loads in flight per wave (4 accumulators, 8-wide unroll).
__global__ __launch_bounds__(256) void gather_kernel(
    const float* __restrict__ X,
    const int* __restrict__ row_start,
    const int* __restrict__ adj,
    float* __restrict__ agg, int n_nodes) {
    int gwid = (blockIdx.x * blockDim.x + threadIdx.x) >> 6;
    int j = threadIdx.x & 63;
    if (gwid >= n_nodes) return;
    int v = gwid;
    float acc = X[v * D_FEAT + j];
    int k = row_start[v];
    int kend = row_start[v + 1];
    float a0 = 0.f, a1 = 0.f, a2 = 0.f, a3 = 0.f;
    for (; k + 8 <= kend; k += 8) {
        int u0 = adj[k + 0], u1 = adj[k + 1], u2 = adj[k + 2], u3 = adj[k + 3];
        int u4 = adj[k + 4], u5 = adj[k + 5], u6 = adj[k + 6], u7 = adj[k + 7];
        float r0 = X[u0 * D_FEAT + j], r1 = X[u1 * D_FEAT + j];
        float r2 = X[u2 * D_FEAT + j], r3 = X[u3 * D_FEAT + j];
        float r4 = X[u4 * D_FEAT + j], r5 = X[u5 * D_FEAT + j];
        float r6 = X[u6 * D_FEAT + j], r7 = X[u7 * D_FEAT + j];
        a0 += r0; a1 += r1; a2 += r2; a3 += r3;
        a0 += r4; a1 += r5; a2 += r6; a3 += r7;
    }
    for (; k < kend; ++k) acc += X[adj[k] * D_FEAT + j];
    agg[v * D_FEAT + j] = acc + (a0 + a1) + (a2 + a3);
}

// ---------------- 2-layer MLP, in-place on d_out ----------------
// Block = 256 = 4 waves; each wave owns 4 nodes. W in LDS; each W-column read
// feeds 4 FMAs. All hot-loop LDS deps are wave-local (no __syncthreads after
// the weight stage). Reads agg rows and overwrites them (per-node, safe).
__global__ __launch_bounds__(256) void mlp_kernel(
    float* __restrict__ agg,   // in-place: also the output
    const float* __restrict__ Wh, const float* __restrict__ bh,
    const float* __restrict__ Wo, const float* __restrict__ bo,
    int n_nodes) {
    __shared__ __align__(16) float wh_lds[D_FEAT * D_FEAT];
    __shared__ __align__(16) float wo_lds[D_FEAT * D_FEAT];
    __shared__ __align__(16) float x_lds[4][4][D_FEAT];
    __shared__ __align__(16) float h_lds[4][4][D_FEAT];

    int tid = threadIdx.x;
    {
        const float4* Wh4 = (const float4*)Wh;
        const float4* Wo4 = (const float4*)Wo;
        float4* wh4 = (float4*)wh_lds;
        float4* wo4 = (float4*)wo_lds;
        for (int i = tid; i < D_FEAT * D_FEAT / 4; i += 256) {
            wh4[i] = Wh4[i];
            wo4[i] = Wo4[i];
        }
    }
    int w = tid >> 6;
    int j = tid & 63;
    float bhj = bh[j];
    float boj = bo[j];
    __syncthreads();

    int vbase = blockIdx.x * 16 + w * 4;

    #pragma unroll
    for (int nb = 0; nb < 4; ++nb) {
        int v = vbase + nb;
        x_lds[w][nb][j] = (v < n_nodes) ? agg[v * D_FEAT + j] : 0.0f;
    }

    // ---- layer 1 ----
    {
        float a0 = bhj, a1 = bhj, a2 = bhj, a3 = bhj;
        const float4* x0 = (const float4*)x_lds[w][0];
        const float4* x1 = (const float4*)x_lds[w][1];
        const float4* x2 = (const float4*)x_lds[w][2];
        const float4* x3 = (const float4*)x_lds[w][3];
        #pragma unroll
        for (int k4 = 0; k4 < 16; ++k4) {
            float4 p0 = x0[k4], p1 = x1[k4], p2 = x2[k4], p3 = x3[k4];
            float w0 = wh_lds[(k4 * 4 + 0) * D_FEAT + j];
            float w1 = wh_lds[(k4 * 4 + 1) * D_FEAT + j];
            float w2 = wh_lds[(k4 * 4 + 2) * D_FEAT + j];
            float w3 = wh_lds[(k4 * 4 + 3) * D_FEAT + j];
            a0 = fmaf(p0.x, w0, a0); a0 = fmaf(p0.y, w1, a0); a0 = fmaf(p0.z, w2, a0); a0 = fmaf(p0.w, w3, a0);
            a1 = fmaf(p1.x, w0, a1); a1 = fmaf(p1.y, w1, a1); a1 = fmaf(p1.z, w2, a1); a1 = fmaf(p1.w, w3, a1);
            a2 = fmaf(p2.x, w0, a2); a2 = fmaf(p2.y, w1, a2); a2 = fmaf(p2.z, w2, a2); a2 = fmaf(p2.w, w3, a2);
            a3 = fmaf(p3.x, w0, a3); a3 = fmaf(p3.y, w1, a3); a3 = fmaf(p3.z, w2, a3); a3 = fmaf(p3.w, w3, a3);
        }
        h_lds[w][0][j] = fmaxf(a0, 0.0f);
        h_lds[w][1][j] = fmaxf(a1, 0.0f);
        h_lds[w][2][j] = fmaxf(a2, 0.0f);
        h_lds[w][3][j] = fmaxf(a3, 0.0f);
    }

    // ---- layer 2 ----
    {
        float a0 = boj, a1 = boj, a2 = boj, a3 = boj;
        const float4* x0 = (const float4*)h_lds[w][0];
        const float4* x1 = (const float4*)h_lds[w][1];
        const float4* x2 = (const float4*)h_lds[w][2];
        const float4* x3 = (const float4*)h_lds[w][3];
        #pragma unroll
        for (int k4 = 0; k4 < 16; ++k4) {
            float4 p0 = x0[k4], p1 = x1[k4], p2 = x2[k4], p3 = x3[k4];
            float w0 = wo_lds[(k4 * 4 + 0) * D_FEAT + j];
            float w1 = wo_lds[(k4 * 4 + 1) * D_FEAT + j];
            float w2 = wo_lds[(k4 * 4 + 2) * D_FEAT + j];
            float w3 = wo_lds[(k4 * 4 + 3) * D_FEAT + j];
            a0 = fmaf(p0.x, w0, a0); a0 = fmaf(p0.y, w1, a0); a0 = fmaf(p0.z, w2, a0); a0 = fmaf(p0.w, w3, a0);
            a1 = fmaf(p1.x, w0, a1); a1 = fmaf(p1.y, w1, a1); a1 = fmaf(p1.z, w2, a1); a1 = fmaf(p1.w, w3, a1);
            a2 = fmaf(p2.x, w0, a2); a2 = fmaf(p2.y, w1, a2); a2 = fmaf(p2.z, w2, a2); a2 = fmaf(p2.w, w3, a2);
            a3 = fmaf(p3.x, w0, a3); a3 = fmaf(p3.y, w1, a3); a3 = fmaf(p3.z, w2, a3); a3 = fmaf(p3.w, w3, a3);
        }
        if (vbase + 0 < n_nodes) agg[(vbase + 0) * D_FEAT + j] = fmaxf(a0, 0.0f);
        if (vbase + 1 < n_nodes) agg[(vbase + 1) * D_FEAT + j] = fmaxf(a1, 0.0f);
        if (vbase + 2 < n_nodes) agg[(vbase + 2) * D_FEAT + j] = fmaxf(a2, 0.0f);
        if (vbase + 3 < n_nodes) agg[(vbase + 3) * D_FEAT + j] = fmaxf(a3, 0.0f);
    }
}

extern "C" void kernel_launch(void* const* d_in, const int* in_sizes, int n_in,
                              void* d_out, int out_size, void* d_ws, size_t ws_size,
                              hipStream_t stream) {
    const float* X     = (const float*)d_in[0];
    const int*   ref_a = (const int*)d_in[1];
    const int*   ref_b = (const int*)d_in[2];
    // d_in[3]=v_map, d_in[4]=v_count : unused by the reference
    const float* Wh    = (const float*)d_in[5];
    const float* bh    = (const float*)d_in[6];
    const float* Wo    = (const float*)d_in[7];
    const float* bo    = (const float*)d_in[8];
    float* out = (float*)d_out;

    int n_nodes = in_sizes[0] / D_FEAT;
    int n_edges = in_sizes[1];
    int nchunks = (n_nodes + SCAN_CHUNK - 1) / SCAN_CHUNK;

    // workspace layout (all int32): ~9.3 MB
    int* deg       = (int*)d_ws;
    int* row_start = deg + n_nodes;              // n_nodes + 1
    int* cursor    = row_start + n_nodes + 1;
    int* bs        = cursor + n_nodes;
    int* adj       = bs + ((nchunks + 3) & ~3);  // 2 * n_edges

    int eb256 = (n_edges + 255) / 256;

    hipMemsetAsync(deg, 0, n_nodes * sizeof(int), stream);
    hist_kernel<<<eb256, 256, 0, stream>>>(ref_a, ref_b, deg, n_edges);
    scan_blocks_kernel<<<nchunks, 256, 0, stream>>>(deg, row_start, bs, n_nodes);
    scan_totals_kernel<<<1, 64, 0, stream>>>(bs, nchunks);
    add_offsets_kernel<<<(n_nodes + 1 + 255) / 256, 256, 0, stream>>>(
        row_start, bs, cursor, n_nodes, 2 * n_edges);
    fill_adj_kernel<<<eb256, 256, 0, stream>>>(ref_a, ref_b, cursor, adj, n_edges);

    // gather into d_out (used as agg), then MLP in-place on d_out
    int gwaves_blocks = (n_nodes * 64 + 255) / 256;   // one wave per node
    gather_kernel<<<gwaves_blocks, 256, 0, stream>>>(X, row_start, adj, out, n_nodes);

    int mblocks = (n_nodes + 15) / 16;
    mlp_kernel<<<mblocks, 256, 0, stream>>>(out, Wh, bh, Wo, bo, n_nodes);
}